// Round 11
// baseline (438.465 us; speedup 1.0000x reference)
//
#include <hip/hip_runtime.h>
#include <math.h>

#define B_SZ    2
#define L_SEQ   2048
#define D_MODEL 1024
#define D_INNER 2048
#define D_STATE 16
#define DT_RANK 64
#define MM      (B_SZ * L_SEQ)   // 4096 rows
#define NCH     32               // scan chunks
#define CLEN    (L_SEQ / NCH)    // 64 steps per chunk
#define PFD     8                // scan prefetch depth

typedef _Float16 h8v __attribute__((ext_vector_type(8)));
typedef _Float16 h4v __attribute__((ext_vector_type(4)));
typedef float f32x4 __attribute__((ext_vector_type(4)));

// Async global->LDS DMA, 16B per lane. LDS dest = uniform base + lane*16.
__device__ __forceinline__ void gload16(const void* g, void* l) {
    __builtin_amdgcn_global_load_lds((const __attribute__((address_space(1))) void*)g,
                                     (__attribute__((address_space(3))) void*)l, 16, 0, 0);
}

// ---------------------------------------------------------------------------
// prep: weight transposes (fp32 -> fp16 T[N][K]) + x cast + conv_w transpose
// + zero-init of out (required: harness poisons d_out, split-K K5 accumulates).
// ---------------------------------------------------------------------------
__global__ __launch_bounds__(256) void prep(const float* __restrict__ x,
                                            _Float16* __restrict__ xf16,
                                            const float* __restrict__ W_in,
                                            _Float16* __restrict__ WinT,
                                            const float* __restrict__ W_x,
                                            _Float16* __restrict__ WxT,
                                            const float* __restrict__ W_dt,
                                            _Float16* __restrict__ WdtT,
                                            const float* __restrict__ W_out,
                                            _Float16* __restrict__ WoutT,
                                            const float* __restrict__ cw,
                                            float* __restrict__ cwT,
                                            float* __restrict__ outz) {
    __shared__ float t[32][33];
    const int b = blockIdx.x;
    const float* W; _Float16* T; int K, N, tile;
    if (b < 4096)      { W = W_in;  T = WinT;  K = 1024; N = 4096; tile = b; }
    else if (b < 4288) { W = W_x;   T = WxT;   K = 2048; N = 96;   tile = b - 4096; }
    else if (b < 4416) { W = W_dt;  T = WdtT;  K = 64;   N = 2048; tile = b - 4288; }
    else if (b < 6464) { W = W_out; T = WoutT; K = 2048; N = 1024; tile = b - 4416; }
    else if (b < 10560) {
        int idx = (b - 6464) * 256 + threadIdx.x;
        float4 v = ((const float4*)x)[idx];
        h4v h = {(_Float16)v.x, (_Float16)v.y, (_Float16)v.z, (_Float16)v.w};
        *(h4v*)(xf16 + (size_t)idx * 4) = h;
        return;
    } else if (b == 10560) {
        // conv_w [2048][4] -> cwT [4][2048]
        for (int i = threadIdx.x; i < D_INNER * 4; i += 256) {
            int d = i >> 2, k = i & 3;
            cwT[k * D_INNER + d] = cw[i];
        }
        return;
    } else {
        // zero out[4096][1024]: 4096 blocks x 256 thr x float4
        int idx = (b - 10561) * 256 + threadIdx.x;
        ((float4*)outz)[idx] = make_float4(0.f, 0.f, 0.f, 0.f);
        return;
    }
    const int ntx = N / 32;
    const int k0 = (tile / ntx) * 32, n0 = (tile % ntx) * 32;
    #pragma unroll
    for (int i = 0; i < 4; ++i) {
        int idx = threadIdx.x + i * 256;
        int r = idx >> 5, c = idx & 31;
        t[r][c] = W[(size_t)(k0 + r) * N + n0 + c];
    }
    __syncthreads();
    #pragma unroll
    for (int i = 0; i < 4; ++i) {
        int idx = threadIdx.x + i * 256;
        int n = idx >> 5, k = idx & 31;
        T[(size_t)(n0 + n) * K + k0 + k] = (_Float16)t[k][n];
    }
}

// ---------------------------------------------------------------------------
// fp16 MFMA GEMM, double-buffered async DMA: C = A[M][lda] @ Bt[N][lda]^T over
// K columns starting at blockIdx.z*K (split-K support; lda = row stride).
// 128x128 tile, 256 thr, 4 waves 2x2, wave 64x64 (4x4 16x16x32 frags), BK=32.
// K-loop: issue DMA(k+1) -> MFMA(k) -> barrier. LDS offsets arithmetic only.
// Epilogue (per-wave LDS transpose -> vectorized/coalesced stores):
// EPI 1: fp16 H = softplus(acc+bias[col]).
// EPI 2: bn<2048 -> fp16 H (xs); bn>=2048 -> silu -> fp16 Hg (gate).
// EPI 3: atomicAdd fp32 into C (split-K accumulate; C pre-zeroed).
// ---------------------------------------------------------------------------
template<int EPI>
__global__ __launch_bounds__(256) void gemm_f16(const _Float16* __restrict__ A,
                                                const _Float16* __restrict__ Bt,
                                                const float* __restrict__ bias,
                                                float* __restrict__ C,
                                                _Float16* __restrict__ H,
                                                _Float16* __restrict__ Hg,
                                                int M, int N, int K, int lda, int ldc) {
    __shared__ _Float16 smemh[16384];   // 32KB: staging dbuf, reused by epilogue

    const int tid = threadIdx.x;
    const int wave = tid >> 6, lane = tid & 63;
    const int bm = blockIdx.y * 128, bn = blockIdx.x * 128;

    // split-K: this block covers columns [kz*K, kz*K + K)
    const size_t kofs = (size_t)blockIdx.z * K;

    const int lrow = lane >> 2, pc = lane & 3;
    const int ar = wave * 32 + lrow;
    const size_t gA = (size_t)(bm + ar) * lda + kofs + ((pc ^ ((ar >> 1) & 3)) * 8);
    const size_t gB = (size_t)(bn + ar) * lda + kofs + ((pc ^ ((ar >> 1) & 3)) * 8);
    const int lofs = (wave * 32) * 32;

    const int lm = lane & 15, lq = lane >> 4;
    const int rofs = (lq ^ ((lm >> 1) & 3)) * 8;
    const int wm = (wave >> 1) * 64, wn = (wave & 1) * 64;

    f32x4 acc[4][4];
    #pragma unroll
    for (int i = 0; i < 4; ++i)
        #pragma unroll
        for (int j = 0; j < 4; ++j) acc[i][j] = (f32x4){0.f, 0.f, 0.f, 0.f};

    // prologue: fill buffer 0  (A buf at kb*4096, B buf at 8192 + kb*4096)
    gload16(A + gA, smemh + lofs);
    gload16(A + gA + (size_t)16 * lda, smemh + lofs + 16 * 32);
    gload16(Bt + gB, smemh + 8192 + lofs);
    gload16(Bt + gB + (size_t)16 * lda, smemh + 8192 + lofs + 16 * 32);
    __syncthreads();

    int kb = 0;
    for (int k0 = 0; k0 < K; k0 += 32, kb ^= 1) {
        if (k0 + 32 < K) {   // issue next tile BEFORE computing this one
            int nb = kb ^ 1;
            gload16(A + gA + k0 + 32, smemh + nb * 4096 + lofs);
            gload16(A + gA + k0 + 32 + (size_t)16 * lda, smemh + nb * 4096 + lofs + 16 * 32);
            gload16(Bt + gB + k0 + 32, smemh + 8192 + nb * 4096 + lofs);
            gload16(Bt + gB + k0 + 32 + (size_t)16 * lda, smemh + 8192 + nb * 4096 + lofs + 16 * 32);
        }

        const _Float16* sA = smemh + kb * 4096;
        const _Float16* sB = smemh + 8192 + kb * 4096;
        h8v fa[4], fb[4];
        #pragma unroll
        for (int i = 0; i < 4; ++i) {
            fa[i] = *(const h8v*)&sA[(wm + i * 16 + lm) * 32 + rofs];
            fb[i] = *(const h8v*)&sB[(wn + i * 16 + lm) * 32 + rofs];
        }
        #pragma unroll
        for (int mi = 0; mi < 4; ++mi)
            #pragma unroll
            for (int ni = 0; ni < 4; ++ni)
                acc[mi][ni] = __builtin_amdgcn_mfma_f32_16x16x32_f16(fa[mi], fb[ni], acc[mi][ni], 0, 0, 0);
        __syncthreads();   // drains next-tile DMA; protects buffer reuse
    }
    // after final barrier all waves are done with staging LDS -> reuse it.

    if (EPI == 3) {
        float* ep = (float*)smemh + wave * 1088;   // 16 x 68 fp32 (padded)
        #pragma unroll
        for (int mi = 0; mi < 4; ++mi) {
            #pragma unroll
            for (int ni = 0; ni < 4; ++ni)
                #pragma unroll
                for (int r = 0; r < 4; ++r)
                    ep[(lq * 4 + r) * 68 + ni * 16 + lm] = acc[mi][ni][r];
            int rowb = bm + wm + mi * 16;
            #pragma unroll
            for (int i = 0; i < 4; ++i) {
                int ch = lane + 64 * i;
                int row = ch >> 4, c4 = (ch & 15) * 4;
                float4 v = *(const float4*)&ep[row * 68 + c4];
                float* dst = &C[(size_t)(rowb + row) * ldc + bn + wn + c4];
                atomicAdd(dst + 0, v.x);
                atomicAdd(dst + 1, v.y);
                atomicAdd(dst + 2, v.z);
                atomicAdd(dst + 3, v.w);
            }
        }
    } else {
        _Float16* ep = smemh + wave * 1152;        // 16 x 72 fp16 (padded, 16B rows)
        const bool gate = (EPI == 2) && (bn >= 2048);
        _Float16* dst = gate ? Hg : H;
        const int cb = bn + wn - (gate ? 2048 : 0);
        #pragma unroll
        for (int mi = 0; mi < 4; ++mi) {
            #pragma unroll
            for (int ni = 0; ni < 4; ++ni) {
                int col = bn + wn + ni * 16 + lm;
                #pragma unroll
                for (int r = 0; r < 4; ++r) {
                    float v = acc[mi][ni][r];
                    if (EPI == 1) {
                        float a = v + bias[col];
                        v = (a > 20.f) ? a : log1pf(__expf(a));
                    } else if (gate) {
                        v = v / (1.f + __expf(-v));
                    }
                    ep[(lq * 4 + r) * 72 + ni * 16 + lm] = (_Float16)v;
                }
            }
            int rowb = bm + wm + mi * 16;
            #pragma unroll
            for (int i = 0; i < 2; ++i) {
                int ch = lane + 64 * i;
                int row = ch >> 3, c8 = (ch & 7) * 8;
                *(h8v*)&dst[(size_t)(rowb + row) * ldc + cb + c8] =
                    *(const h8v*)&ep[row * 72 + c8];
            }
        }
    }
}

// ---------------------------------------------------------------------------
// Skinny fp16 MFMA GEMM for x_dbl: xd[4096][96] = xch @ WxT^T.
// 32 rows/block -> 128 blocks (was 64 rows/64 blocks = 1/4 CU utilization).
// 4 waves: rows (wave&1)*16, col-group (wave>>1)*48 (3 n-frags). 8 KB LDS.
// Epilogue scatters: 0..63 -> xdh fp16, 64..79 -> Bm, 80..95 -> Cm.
// ---------------------------------------------------------------------------
__global__ __launch_bounds__(256) void gemm_xd(const _Float16* __restrict__ xch,
                                               const _Float16* __restrict__ WxT,
                                               _Float16* __restrict__ xdh,
                                               float* __restrict__ Bm,
                                               float* __restrict__ Cm) {
    __shared__ _Float16 sm[1024 + 96 * 32];   // A: 32x32 @0, B: 96x32 @1024
    const int tid = threadIdx.x;
    const int m0 = blockIdx.x * 32;
    const int wave = tid >> 6, lane = tid & 63;
    const int lm = lane & 15, lq = lane >> 4;
    const int rofs = (lq ^ ((lm >> 1) & 3)) * 8;
    const int wrow = (wave & 1) * 16;      // wave's row group
    const int wcol = (wave >> 1) * 48;     // wave's col group

    // staging: 512 items (A: 0..127 = 32 rows x 4 chunks; B: 128..511 = 96 x 4)
    const bool isA0 = tid < 128;
    const int r0 = isA0 ? (tid >> 2) : ((tid - 128) >> 2);
    const int ch0 = tid & 3;
    const int r1 = (tid + 128) >> 2;       // B rows 32..95
    const int ch1 = tid & 3;
    const _Float16* g0 = isA0 ? xch + (size_t)(m0 + r0) * D_INNER + ch0 * 8
                              : WxT + (size_t)r0 * D_INNER + ch0 * 8;
    const _Float16* g1 = WxT + (size_t)r1 * D_INNER + ch1 * 8;
    const int wofs0 = (isA0 ? 0 : 1024) + r0 * 32 + ((ch0 ^ ((r0 >> 1) & 3)) * 8);
    const int wofs1 = 1024 + r1 * 32 + ((ch1 ^ ((r1 >> 1) & 3)) * 8);

    f32x4 acc[3];
    #pragma unroll
    for (int i = 0; i < 3; ++i) acc[i] = (f32x4){0.f, 0.f, 0.f, 0.f};

    h8v p0 = *(const h8v*)g0;
    h8v p1 = *(const h8v*)g1;

    for (int k0 = 0; k0 < D_INNER; k0 += 32) {
        *(h8v*)&sm[wofs0] = p0;
        *(h8v*)&sm[wofs1] = p1;
        __syncthreads();

        if (k0 + 32 < D_INNER) {
            p0 = *(const h8v*)(g0 + k0 + 32);
            p1 = *(const h8v*)(g1 + k0 + 32);
        }

        h8v fa = *(const h8v*)&sm[(wrow + lm) * 32 + rofs];
        #pragma unroll
        for (int nf = 0; nf < 3; ++nf) {
            h8v fb = *(const h8v*)&sm[1024 + (wcol + nf * 16 + lm) * 32 + rofs];
            acc[nf] = __builtin_amdgcn_mfma_f32_16x16x32_f16(fa, fb, acc[nf], 0, 0, 0);
        }
        __syncthreads();
    }

    #pragma unroll
    for (int nf = 0; nf < 3; ++nf) {
        int col = wcol + nf * 16 + lm;
        #pragma unroll
        for (int r = 0; r < 4; ++r) {
            int row = m0 + wrow + lq * 4 + r;
            float v = acc[nf][r];
            if (col < 64)      xdh[(size_t)row * 64 + col] = (_Float16)v;
            else if (col < 80) Bm[(size_t)row * 16 + (col - 64)] = v;
            else               Cm[(size_t)row * 16 + (col - 80)] = v;
        }
    }
}

// ---------------------------------------------------------------------------
// Depthwise causal conv (k=4) + bias + SiLU, 8 elements/thread, cwT weights.
// ---------------------------------------------------------------------------
__global__ __launch_bounds__(256) void conv_silu(const _Float16* __restrict__ xsh,
                                                 const float* __restrict__ cwT,
                                                 const float* __restrict__ cb,
                                                 _Float16* __restrict__ xch) {
    int idx = blockIdx.x * 256 + threadIdx.x;
    int d0 = (idx * 8) & (D_INNER - 1);
    int m  = (idx * 8) >> 11;
    int l  = m & (L_SEQ - 1);
    float acc[8];
    {
        float4 c0 = *(const float4*)&cb[d0];
        float4 c1 = *(const float4*)&cb[d0 + 4];
        acc[0] = c0.x; acc[1] = c0.y; acc[2] = c0.z; acc[3] = c0.w;
        acc[4] = c1.x; acc[5] = c1.y; acc[6] = c1.z; acc[7] = c1.w;
    }
    #pragma unroll
    for (int k = 0; k < 4; ++k) {
        int ll = l - 3 + k;
        if (ll >= 0) {
            h8v v = *(const h8v*)(xsh + (size_t)(m - 3 + k) * D_INNER + d0);
            float4 w0 = *(const float4*)&cwT[k * D_INNER + d0];
            float4 w1 = *(const float4*)&cwT[k * D_INNER + d0 + 4];
            acc[0] += (float)v[0] * w0.x; acc[1] += (float)v[1] * w0.y;
            acc[2] += (float)v[2] * w0.z; acc[3] += (float)v[3] * w0.w;
            acc[4] += (float)v[4] * w1.x; acc[5] += (float)v[5] * w1.y;
            acc[6] += (float)v[6] * w1.z; acc[7] += (float)v[7] * w1.w;
        }
    }
    h8v o;
    #pragma unroll
    for (int j = 0; j < 8; ++j) {
        float s = acc[j] / (1.f + __expf(-acc[j]));
        o[j] = (_Float16)s;
    }
    *(h8v*)(xch + (size_t)idx * 8) = o;
}

// ---------------------------------------------------------------------------
// Scan pass 1: per (b, chunk, d) chunk-local final state (h0=0) + S=sum(delta).
// ---------------------------------------------------------------------------
__global__ __launch_bounds__(256) void scan_part1(const _Float16* __restrict__ deltah,
                                                  const _Float16* __restrict__ xch,
                                                  const float* __restrict__ Bm,
                                                  const float* __restrict__ A_log,
                                                  float* __restrict__ hlocal,
                                                  float* __restrict__ Ssum) {
    const int t = threadIdx.x;
    const int d = blockIdx.x * 256 + t;
    const int c = blockIdx.y;
    const int b = blockIdx.z;

    float An[16];
    {
        const float4* ap = (const float4*)(A_log + (size_t)d * 16);
        #pragma unroll
        for (int q = 0; q < 4; ++q) {
            float4 v = ap[q];
            An[q * 4 + 0] = -__expf(v.x); An[q * 4 + 1] = -__expf(v.y);
            An[q * 4 + 2] = -__expf(v.z); An[q * 4 + 3] = -__expf(v.w);
        }
    }
    const float An0 = An[0];
    bool fast = An0 < 0.f;
    #pragma unroll
    for (int n = 0; n < 16; ++n)
        fast = fast && (fabsf(An[n] - (float)(n + 1) * An0) < 1e-3f * fabsf(An[n]));

    __shared__ float sB[CLEN][16];
    {
        size_t l0 = (size_t)(b * L_SEQ + c * CLEN) * 16;
        #pragma unroll
        for (int i = 0; i < (CLEN * 16) / 256; ++i) {
            int idx = t + i * 256;
            sB[idx >> 4][idx & 15] = Bm[l0 + idx];
        }
    }
    __syncthreads();

    float h[16];
    #pragma unroll
    for (int n = 0; n < 16; ++n) h[n] = 0.f;
    float S = 0.f;

    size_t base = (size_t)(b * L_SEQ + c * CLEN) * D_INNER + d;
    float bd[PFD], bx[PFD];
    #pragma unroll
    for (int i = 0; i < PFD; ++i) {
        bd[i] = (float)deltah[base + (size_t)i * D_INNER];
        bx[i] = (float)xch[base + (size_t)i * D_INNER];
    }

    if (fast) {
        for (int jb = 0; jb < CLEN; jb += PFD) {
            #pragma unroll
            for (int i = 0; i < PFD; ++i) {
                int j = jb + i;
                float dv = bd[i], xv = bx[i];
                int jn = j + PFD;
                if (jn < CLEN) {
                    bd[i] = (float)deltah[base + (size_t)jn * D_INNER];
                    bx[i] = (float)xch[base + (size_t)jn * D_INNER];
                }
                S += dv;
                float dbx = dv * xv;
                float r = __expf(dv * An0);
                float pw = r;
                #pragma unroll
                for (int n = 0; n < 16; ++n) {
                    h[n] = pw * h[n] + dbx * sB[j][n];
                    pw *= r;
                }
            }
        }
    } else {
        for (int jb = 0; jb < CLEN; jb += PFD) {
            #pragma unroll
            for (int i = 0; i < PFD; ++i) {
                int j = jb + i;
                float dv = bd[i], xv = bx[i];
                int jn = j + PFD;
                if (jn < CLEN) {
                    bd[i] = (float)deltah[base + (size_t)jn * D_INNER];
                    bx[i] = (float)xch[base + (size_t)jn * D_INNER];
                }
                S += dv;
                float dbx = dv * xv;
                #pragma unroll
                for (int n = 0; n < 16; ++n)
                    h[n] = __expf(dv * An[n]) * h[n] + dbx * sB[j][n];
            }
        }
    }

    size_t o = ((size_t)(b * NCH + c) * D_INNER + d) * 16;
    float4* hp = (float4*)(hlocal + o);
    #pragma unroll
    for (int q = 0; q < 4; ++q)
        hp[q] = make_float4(h[q * 4], h[q * 4 + 1], h[q * 4 + 2], h[q * 4 + 3]);
    Ssum[(size_t)(b * NCH + c) * D_INNER + d] = S;
}

// ---------------------------------------------------------------------------
// Combine: sequential over NCH chunks per (b,d,n); writes each chunk's h0.
// ---------------------------------------------------------------------------
__global__ __launch_bounds__(256) void scan_combine(const float* __restrict__ hlocal,
                                                    const float* __restrict__ Ssum,
                                                    const float* __restrict__ A_log,
                                                    float* __restrict__ h0buf) {
    int gid = blockIdx.x * 256 + threadIdx.x;
    int n = gid & 15;
    int d = (gid >> 4) & (D_INNER - 1);
    int b = gid >> 15;
    float An = -__expf(A_log[(size_t)d * 16 + n]);
    float H = 0.f;
    float pS[4], pH[4];
    #pragma unroll
    for (int i = 0; i < 4; ++i) {
        size_t sc = (size_t)(b * NCH + i) * D_INNER + d;
        pS[i] = Ssum[sc];
        pH[i] = hlocal[sc * 16 + n];
    }
    for (int cb = 0; cb < NCH; cb += 4) {
        #pragma unroll
        for (int i = 0; i < 4; ++i) {
            int c = cb + i;
            float S = pS[i], hl = pH[i];
            int cn = c + 4;
            if (cn < NCH) {
                size_t sc = (size_t)(b * NCH + cn) * D_INNER + d;
                pS[i] = Ssum[sc];
                pH[i] = hlocal[sc * 16 + n];
            }
            size_t o = ((size_t)(b * NCH + c) * D_INNER + d) * 16 + n;
            h0buf[o] = H;
            H = __expf(An * S) * H + hl;
        }
    }
}

// ---------------------------------------------------------------------------
// Scan pass 2: replay from h0; y = sum_n h*C; fuse +xc*D and *pre-silu'd gate;
// write y fp16 (A-operand of the output GEMM).
// ---------------------------------------------------------------------------
__global__ __launch_bounds__(256) void scan_part2(const _Float16* __restrict__ deltah,
                                                  const _Float16* __restrict__ xch,
                                                  const float* __restrict__ Bm,
                                                  const float* __restrict__ Cm,
                                                  const float* __restrict__ h0buf,
                                                  const float* __restrict__ A_log,
                                                  const float* __restrict__ Dp,
                                                  const _Float16* __restrict__ sresh,
                                                  _Float16* __restrict__ yhalf) {
    const int t = threadIdx.x;
    const int d = blockIdx.x * 256 + t;
    const int c = blockIdx.y;
    const int b = blockIdx.z;

    float An[16];
    {
        const float4* ap = (const float4*)(A_log + (size_t)d * 16);
        #pragma unroll
        for (int q = 0; q < 4; ++q) {
            float4 v = ap[q];
            An[q * 4 + 0] = -__expf(v.x); An[q * 4 + 1] = -__expf(v.y);
            An[q * 4 + 2] = -__expf(v.z); An[q * 4 + 3] = -__expf(v.w);
        }
    }
    const float An0 = An[0];
    bool fast = An0 < 0.f;
    #pragma unroll
    for (int n = 0; n < 16; ++n)
        fast = fast && (fabsf(An[n] - (float)(n + 1) * An0) < 1e-3f * fabsf(An[n]));

    __shared__ float sB[CLEN][16];
    __shared__ float sC[CLEN][16];
    {
        size_t l0 = (size_t)(b * L_SEQ + c * CLEN) * 16;
        #pragma unroll
        for (int i = 0; i < (CLEN * 16) / 256; ++i) {
            int idx = t + i * 256;
            sB[idx >> 4][idx & 15] = Bm[l0 + idx];
            sC[idx >> 4][idx & 15] = Cm[l0 + idx];
        }
    }
    __syncthreads();

    float h[16];
    {
        size_t o = ((size_t)(b * NCH + c) * D_INNER + d) * 16;
        const float4* hp = (const float4*)(h0buf + o);
        #pragma unroll
        for (int q = 0; q < 4; ++q) {
            float4 v = hp[q];
            h[q * 4 + 0] = v.x; h[q * 4 + 1] = v.y;
            h[q * 4 + 2] = v.z; h[q * 4 + 3] = v.w;
        }
    }
    const float Dv = Dp[d];

    size_t base = (size_t)(b * L_SEQ + c * CLEN) * D_INNER + d;
    float bd[PFD], bx[PFD], bg[PFD];
    #pragma unroll
    for (int i = 0; i < PFD; ++i) {
        bd[i] = (float)deltah[base + (size_t)i * D_INNER];
        bx[i] = (float)xch[base + (size_t)i * D_INNER];
        bg[i] = (float)sresh[base + (size_t)i * D_INNER];
    }

    if (fast) {
        for (int jb = 0; jb < CLEN; jb += PFD) {
            #pragma unroll
            for (int i = 0; i < PFD; ++i) {
                int j = jb + i;
                float dv = bd[i], xv = bx[i], gv = bg[i];
                int jn = j + PFD;
                if (jn < CLEN) {
                    bd[i] = (float)deltah[base + (size_t)jn * D_INNER];
                    bx[i] = (float)xch[base + (size_t)jn * D_INNER];
                    bg[i] = (float)sresh[base + (size_t)jn * D_INNER];
                }
                float dbx = dv * xv;
                float r = __expf(dv * An0);
                float pw = r;
                float y = 0.f;
                #pragma unroll
                for (int n = 0; n < 16; ++n) {
                    h[n] = pw * h[n] + dbx * sB[j][n];
                    y += h[n] * sC[j][n];
                    pw *= r;
                }
                float yv = (y + xv * Dv) * gv;
                yhalf[base + (size_t)j * D_INNER] = (_Float16)yv;
            }
        }
    } else {
        for (int jb = 0; jb < CLEN; jb += PFD) {
            #pragma unroll
            for (int i = 0; i < PFD; ++i) {
                int j = jb + i;
                float dv = bd[i], xv = bx[i], gv = bg[i];
                int jn = j + PFD;
                if (jn < CLEN) {
                    bd[i] = (float)deltah[base + (size_t)jn * D_INNER];
                    bx[i] = (float)xch[base + (size_t)jn * D_INNER];
                    bg[i] = (float)sresh[base + (size_t)jn * D_INNER];
                }
                float dbx = dv * xv;
                float y = 0.f;
                #pragma unroll
                for (int n = 0; n < 16; ++n) {
                    h[n] = __expf(dv * An[n]) * h[n] + dbx * sB[j][n];
                    y += h[n] * sC[j][n];
                }
                float yv = (y + xv * Dv) * gv;
                yhalf[base + (size_t)j * D_INNER] = (_Float16)yv;
            }
        }
    }
}

extern "C" void kernel_launch(void* const* d_in, const int* in_sizes, int n_in,
                              void* d_out, int out_size, void* d_ws, size_t ws_size,
                              hipStream_t stream) {
    const float* x      = (const float*)d_in[0];
    const float* W_in   = (const float*)d_in[1];
    const float* conv_w = (const float*)d_in[2];
    const float* conv_b = (const float*)d_in[3];
    const float* W_x    = (const float*)d_in[4];
    const float* W_dt   = (const float*)d_in[5];
    const float* b_dt   = (const float*)d_in[6];
    const float* A_log  = (const float*)d_in[7];
    const float* D_par  = (const float*)d_in[8];
    const float* W_out  = (const float*)d_in[9];
    float* out = (float*)d_out;

    char* wsb = (char*)d_ws;
    _Float16*  xsh    = (_Float16*)(wsb + 0);             // 16,777,216 B
    _Float16*  sresh  = (_Float16*)(wsb + 16777216);      // 16,777,216 B
    _Float16*  deltah = (_Float16*)(wsb + 33554432);      // 16,777,216 B
    _Float16*  xch    = (_Float16*)(wsb + 50331648);      // 16,777,216 B
    _Float16*  xf16   = (_Float16*)(wsb + 67108864);      //  8,388,608 B (dead after K1)
    _Float16*  WinT   = (_Float16*)(wsb + 75497472);      //  8,388,608 B (dead after K1)
    _Float16*  yhalf  = (_Float16*)(wsb + 67108864);      // 16,777,216 B (aliases xf16+WinT)
    _Float16*  WxT    = (_Float16*)(wsb + 83886080);      //    393,216 B
    _Float16*  WdtT   = (_Float16*)(wsb + 84279296);      //    262,144 B
    _Float16*  xdh    = (_Float16*)(wsb + 84541440);      //    524,288 B
    float*     Bbuf   = (float*)(wsb + 85065728);         //    262,144 B
    float*     Cbuf   = (float*)(wsb + 85327872);         //    262,144 B
    float*     Ssum   = (float*)(wsb + 85590016);         //  1,048,576 B (NCH=32 uses half)
    float*     hloc   = (float*)(wsb + 86638592);         // 16,777,216 B (NCH=32 uses half)
    float*     h0buf  = (float*)(wsb + 103415808);        // 16,777,216 B (NCH=32 uses half)
    _Float16*  WoutT  = (_Float16*)(wsb + 120193024);     //  4,194,304 B
    float*     cwT    = (float*)(wsb + 124387328);        //     32,768 B
    // end: 124,420,096 B

    dim3 blk(256);

    // 1. fused prep: weight transposes + x cast + conv_w transpose + out zero
    prep<<<dim3(14657), blk, 0, stream>>>(x, xf16, W_in, WinT, W_x, WxT,
                                          W_dt, WdtT, W_out, WoutT, conv_w, cwT, out);
    // 2. K1: [xs fp16 | silu(res) fp16] = x @ W_in  (M=4096, N=4096, K=1024)
    gemm_f16<2><<<dim3(32, 32), blk, 0, stream>>>(
        xf16, WinT, nullptr, nullptr, xsh, sresh, MM, 2 * D_INNER, D_MODEL, D_MODEL, 2048);
    // 3. conv + SiLU -> xch fp16
    conv_silu<<<dim3((size_t)MM * D_INNER / 8 / 256), blk, 0, stream>>>(xsh, cwT, conv_b, xch);
    // 4. xd = xc @ W_x (skinny, 128 blocks): xdh fp16 + B, C fp32
    gemm_xd<<<dim3(MM / 32), blk, 0, stream>>>(xch, WxT, xdh, Bbuf, Cbuf);
    // 5. delta = softplus(xd @ W_dt + b_dt) -> fp16  (M=4096, N=2048, K=64)
    gemm_f16<1><<<dim3(16, 32), blk, 0, stream>>>(
        xdh, WdtT, b_dt, nullptr, deltah, nullptr, MM, D_INNER, DT_RANK, DT_RANK, D_INNER);
    // 6. scan pass 1
    scan_part1<<<dim3(D_INNER / 256, NCH, B_SZ), blk, 0, stream>>>(deltah, xch, Bbuf, A_log, hloc, Ssum);
    // 7. combine
    scan_combine<<<dim3(B_SZ * D_INNER * 16 / 256), blk, 0, stream>>>(hloc, Ssum, A_log, h0buf);
    // 8. scan pass 2 (+gating) -> yhalf fp16
    scan_part2<<<dim3(D_INNER / 256, NCH, B_SZ), blk, 0, stream>>>(deltah, xch, Bbuf, Cbuf, h0buf, A_log, D_par, sresh, yhalf);
    // 9. K5: out += y @ W_out, split-K=2 (M=4096, N=1024, K=2x1024, lda=2048)
    gemm_f16<3><<<dim3(8, 32, 2), blk, 0, stream>>>(
        yhalf, WoutT, nullptr, out, nullptr, nullptr, MM, D_MODEL, D_INNER / 2, D_INNER, D_MODEL);
}